// Round 1
// baseline (2550.753 us; speedup 1.0000x reference)
//
#include <hip/hip_runtime.h>
#include <cstdint>

typedef _Float16 f16;
using f16x2 = __attribute__((ext_vector_type(2))) _Float16;
using f16x4 = __attribute__((ext_vector_type(4))) _Float16;
using f16x8 = __attribute__((ext_vector_type(8))) _Float16;
using f32x4 = __attribute__((ext_vector_type(4))) float;
using u32x4 = __attribute__((ext_vector_type(4))) uint32_t;

__device__ __forceinline__ float fdot2(uint32_t w, uint32_t h, float acc) {
#if __has_builtin(__builtin_amdgcn_fdot2)
  return __builtin_amdgcn_fdot2(__builtin_bit_cast(f16x2, w),
                                __builtin_bit_cast(f16x2, h), acc, false);
#else
  f16x2 a = __builtin_bit_cast(f16x2, w), b = __builtin_bit_cast(f16x2, h);
  return acc + (float)a[0] * (float)b[0] + (float)a[1] * (float)b[1];
#endif
}

__device__ __forceinline__ float sigmoidf_(float x) {
  float e = exp2f(-x * 1.44269504088896f);
  return 1.0f / (1.0f + e);
}
__device__ __forceinline__ float tanhf_(float x) {
  float e = exp2f(x * 2.88539008177793f);   // exp(2x)
  return 1.0f - 2.0f / (e + 1.0f);
}

// ---------------- conversion / prep kernels ----------------

__global__ void f32_to_f16_kernel(const float* __restrict__ in, f16* __restrict__ out, long n4) {
  long stride = (long)gridDim.x * blockDim.x;
  for (long i = blockIdx.x * (long)blockDim.x + threadIdx.x; i < n4; i += stride) {
    f32x4 v = *(const f32x4*)(in + i * 4);
    f16x4 h;
    h[0] = (f16)v[0]; h[1] = (f16)v[1]; h[2] = (f16)v[2]; h[3] = (f16)v[3];
    *(f16x4*)(out + i * 4) = h;
  }
}

__global__ void addvec_kernel(const float* __restrict__ a, const float* __restrict__ b,
                              float* __restrict__ o, int n) {
  int i = blockIdx.x * blockDim.x + threadIdx.x;
  if (i < n) o[i] = a[i] + b[i];
}

// wprep[p*1024 + r] = pack(whh[r][2p], whh[r][2p+1]) as f16x2, p<128, r<1024
__global__ void wprep_kernel(const float* __restrict__ whh, uint32_t* __restrict__ wp) {
  int i = blockIdx.x * blockDim.x + threadIdx.x;  // 131072 threads
  int p = i >> 10, r = i & 1023;
  float lo = whh[r * 256 + 2 * p];
  float hi = whh[r * 256 + 2 * p + 1];
  f16x2 h;
  h[0] = (f16)lo; h[1] = (f16)hi;
  wp[i] = __builtin_bit_cast(uint32_t, h);
}

// ---------------- GEMM: C[m,n] = sum_k A[m,k]*B[n,k] + bias[n] ----------------
// A [M,K] f16 row-major, B [N,K] f16 row-major. 128x128 tile, BK=32, 256 thr.

template <int OUTF32>
__global__ __launch_bounds__(256) void gemm_bt_kernel(
    const f16* __restrict__ A, const f16* __restrict__ B,
    const float* __restrict__ bias, void* __restrict__ Cout,
    int M, int N, int K) {
  __shared__ __align__(16) f16 Al[128 * 32];
  __shared__ __align__(16) f16 Bl[128 * 32];
  const int tid = threadIdx.x;
  const int lane = tid & 63, wave = tid >> 6;
  const int bn = blockIdx.x, bm = blockIdx.y;
  const int qm = (wave >> 1) * 64, qn = (wave & 1) * 64;

  f32x4 acc[4][4];
#pragma unroll
  for (int i = 0; i < 4; ++i)
#pragma unroll
    for (int j = 0; j < 4; ++j) acc[i][j] = (f32x4){0.f, 0.f, 0.f, 0.f};

  const int c0 = tid, c1 = 256 + tid;
  const int row0 = c0 >> 2, off0 = c0 & 3;
  const int row1 = c1 >> 2, off1 = c1 & 3;
  const int gmA0 = min(bm * 128 + row0, M - 1);
  const int gmA1 = min(bm * 128 + row1, M - 1);
  const int gnB0 = min(bn * 128 + row0, N - 1);
  const int gnB1 = min(bn * 128 + row1, N - 1);

  for (int k0 = 0; k0 < K; k0 += 32) {
    u32x4 ar0 = *(const u32x4*)(A + (size_t)gmA0 * K + k0 + off0 * 8);
    u32x4 ar1 = *(const u32x4*)(A + (size_t)gmA1 * K + k0 + off1 * 8);
    u32x4 br0 = *(const u32x4*)(B + (size_t)gnB0 * K + k0 + off0 * 8);
    u32x4 br1 = *(const u32x4*)(B + (size_t)gnB1 * K + k0 + off1 * 8);
    __syncthreads();  // previous iteration's LDS reads done
    *(u32x4*)&Al[c0 * 8] = ar0;
    *(u32x4*)&Al[c1 * 8] = ar1;
    *(u32x4*)&Bl[c0 * 8] = br0;
    *(u32x4*)&Bl[c1 * 8] = br1;
    __syncthreads();
    f16x8 af[4], bf[4];
#pragma unroll
    for (int mt = 0; mt < 4; ++mt)
      af[mt] = *(const f16x8*)&Al[(qm + mt * 16 + (lane & 15)) * 32 + (lane >> 4) * 8];
#pragma unroll
    for (int nt = 0; nt < 4; ++nt)
      bf[nt] = *(const f16x8*)&Bl[(qn + nt * 16 + (lane & 15)) * 32 + (lane >> 4) * 8];
#pragma unroll
    for (int mt = 0; mt < 4; ++mt)
#pragma unroll
      for (int nt = 0; nt < 4; ++nt)
        acc[mt][nt] = __builtin_amdgcn_mfma_f32_16x16x32_f16(af[mt], bf[nt], acc[mt][nt], 0, 0, 0);
  }

#pragma unroll
  for (int mt = 0; mt < 4; ++mt)
#pragma unroll
    for (int nt = 0; nt < 4; ++nt)
#pragma unroll
      for (int j = 0; j < 4; ++j) {
        int gm = bm * 128 + qm + mt * 16 + (lane >> 4) * 4 + j;
        int gn = bn * 128 + qn + nt * 16 + (lane & 15);
        if (gm < M && gn < N) {
          float v = acc[mt][nt][j] + bias[gn];
          if (OUTF32)
            ((float*)Cout)[(size_t)gm * N + gn] = v;
          else
            ((f16*)Cout)[(size_t)gm * N + gn] = (f16)v;
        }
      }
}

// ---------------- persistent LSTM recurrence ----------------
// 64 blocks (1 batch each) x 512 threads. Thread t owns gate rows t and t+512.
// Weights: pairs 0..103 in VGPR (208 regs), pairs 104..127 in LDS (stride 28 dwords).
// h broadcast in LDS as packed f16 pairs (128 dwords).

#define RP 104
#define LP 24
#define LSTRIDE 28

__global__ __launch_bounds__(512) void lstm_rec_kernel(
    const f16* __restrict__ xg,       // [B*T, 1024], biases already included
    const uint32_t* __restrict__ wprep,  // [128][1024] packed f16x2
    f16* __restrict__ h_out,          // [B*T, 256]
    int T) {
  __shared__ uint32_t lds_w[1024 * LSTRIDE];  // 112 KB
  __shared__ float gates[1024];               // 4 KB
  __shared__ __align__(16) uint32_t h_pairs[128];  // 512 B
  const int b = blockIdx.x;
  const int tid = threadIdx.x;

  uint32_t w0[RP], w1[RP];
#pragma unroll
  for (int p = 0; p < RP; ++p) {
    w0[p] = wprep[p * 1024 + tid];
    w1[p] = wprep[p * 1024 + tid + 512];
  }
#pragma unroll
  for (int p = 0; p < LP; ++p) {
    lds_w[tid * LSTRIDE + p]         = wprep[(RP + p) * 1024 + tid];
    lds_w[(tid + 512) * LSTRIDE + p] = wprep[(RP + p) * 1024 + tid + 512];
  }
  if (tid < 128) h_pairs[tid] = 0;
  float c_state = 0.0f;
  __syncthreads();

  const f16* xgb = xg + (size_t)b * T * 1024;
  f16* hob = h_out + (size_t)b * T * 256;
  f16 xr0 = xgb[tid], xr1 = xgb[tid + 512];

  for (int t = 0; t < T; ++t) {
    f16 nx0 = (f16)0.f, nx1 = (f16)0.f;
    if (t + 1 < T) {
      nx0 = xgb[(size_t)(t + 1) * 1024 + tid];
      nx1 = xgb[(size_t)(t + 1) * 1024 + tid + 512];
    }
    float a0 = (float)xr0, a1 = (float)xr1;  // even-chunk chains
    float e0 = 0.f, e1 = 0.f;                // odd-chunk chains
    const u32x4* hq = (const u32x4*)h_pairs;
#pragma unroll
    for (int ch = 0; ch < 26; ++ch) {
      u32x4 hv = hq[ch];
#pragma unroll
      for (int q = 0; q < 4; ++q) {
        const int p = ch * 4 + q;
        if (q & 1) { e0 = fdot2(w0[p], hv[q], e0); e1 = fdot2(w1[p], hv[q], e1); }
        else       { a0 = fdot2(w0[p], hv[q], a0); a1 = fdot2(w1[p], hv[q], a1); }
      }
    }
#pragma unroll
    for (int cc = 0; cc < 6; ++cc) {
      u32x4 hv = hq[26 + cc];
      u32x4 wv0 = *(const u32x4*)&lds_w[tid * LSTRIDE + cc * 4];
      u32x4 wv1 = *(const u32x4*)&lds_w[(tid + 512) * LSTRIDE + cc * 4];
#pragma unroll
      for (int q = 0; q < 4; ++q) {
        if (q & 1) { e0 = fdot2(wv0[q], hv[q], e0); e1 = fdot2(wv1[q], hv[q], e1); }
        else       { a0 = fdot2(wv0[q], hv[q], a0); a1 = fdot2(wv1[q], hv[q], a1); }
      }
    }
    gates[tid] = a0 + e0;
    gates[tid + 512] = a1 + e1;
    __syncthreads();
    if (tid < 256) {
      float gi = gates[tid], gf = gates[tid + 256];
      float gg = gates[tid + 512], go = gates[tid + 768];
      float iv = sigmoidf_(gi), fv = sigmoidf_(gf);
      float gv = tanhf_(gg), ov = sigmoidf_(go);
      c_state = fv * c_state + iv * gv;
      float hval = ov * tanhf_(c_state);
      f16 hh = (f16)hval;
      ((f16*)h_pairs)[tid] = hh;
      hob[(size_t)t * 256 + tid] = hh;
    }
    __syncthreads();
    xr0 = nx0; xr1 = nx1;
  }
}

// ---------------- fused LayerNorm + attention pooling ----------------
// one block per batch, 256 threads.

__global__ __launch_bounds__(256) void ln_attn_kernel(
    const f16* __restrict__ h2, const float* __restrict__ lnw,
    const float* __restrict__ lnb, const float* __restrict__ aw,
    f16* __restrict__ att_out) {
  const int b = blockIdx.x, tid = threadIdx.x;
  const int lane = tid & 63, wave = tid >> 6;
  __shared__ float smu[512], sis[512], ssc[512];
  __shared__ float vbuf[256];
  __shared__ float red[16];

  float vj = aw[tid] * lnw[tid];
  float uj = aw[tid] * lnb[tid];
  vbuf[tid] = vj;
  float rv = vj, ru = uj;
#pragma unroll
  for (int m = 1; m < 64; m <<= 1) { rv += __shfl_xor(rv, m, 64); ru += __shfl_xor(ru, m, 64); }
  if (lane == 0) { red[wave] = rv; red[4 + wave] = ru; }
  __syncthreads();
  const float Vsum = red[0] + red[1] + red[2] + red[3];
  const float Csum = red[4] + red[5] + red[6] + red[7];
  const f32x4 v4 = *(const f32x4*)&vbuf[lane * 4];
  const f16* hb = h2 + (size_t)b * 512 * 256;

  for (int tt = wave; tt < 512; tt += 4) {
    f16x4 hv = *(const f16x4*)(hb + (size_t)tt * 256 + lane * 4);
    float h0 = (float)hv[0], h1 = (float)hv[1], h2v = (float)hv[2], h3 = (float)hv[3];
    float s1 = h0 + h1 + h2v + h3;
    float s2 = h0 * h0 + h1 * h1 + h2v * h2v + h3 * h3;
    float sv = h0 * v4[0] + h1 * v4[1] + h2v * v4[2] + h3 * v4[3];
#pragma unroll
    for (int m = 1; m < 64; m <<= 1) {
      s1 += __shfl_xor(s1, m, 64);
      s2 += __shfl_xor(s2, m, 64);
      sv += __shfl_xor(sv, m, 64);
    }
    if (lane == 0) {
      float mu = s1 * (1.0f / 256.0f);
      float var = s2 * (1.0f / 256.0f) - mu * mu;
      float is = rsqrtf(var + 1e-5f);
      smu[tt] = mu; sis[tt] = is;
      ssc[tt] = (sv - mu * Vsum) * is + Csum;
    }
  }
  __syncthreads();
  // softmax over 512 scores
  float a0 = ssc[tid], a1 = ssc[tid + 256];
  float mx = fmaxf(a0, a1);
#pragma unroll
  for (int m = 1; m < 64; m <<= 1) mx = fmaxf(mx, __shfl_xor(mx, m, 64));
  if (lane == 0) red[wave] = mx;
  __syncthreads();
  mx = fmaxf(fmaxf(red[0], red[1]), fmaxf(red[2], red[3]));
  __syncthreads();  // protect red reuse
  float p0 = exp2f((a0 - mx) * 1.44269504f);
  float p1 = exp2f((a1 - mx) * 1.44269504f);
  float ps = p0 + p1;
  float pm = p0 * smu[tid] * sis[tid] + p1 * smu[tid + 256] * sis[tid + 256];
#pragma unroll
  for (int m = 1; m < 64; m <<= 1) { ps += __shfl_xor(ps, m, 64); pm += __shfl_xor(pm, m, 64); }
  if (lane == 0) { red[wave] = ps; red[8 + wave] = pm; }
  __syncthreads();
  const float S = red[0] + red[1] + red[2] + red[3];
  const float PM = (red[8] + red[9] + red[10] + red[11]) / S;
  ssc[tid] = p0 / S * sis[tid];          // alpha_t
  ssc[tid + 256] = p1 / S * sis[tid + 256];
  __syncthreads();
  // pass 2: attended_j = lnw_j*(sum_t alpha_t h_tj - PM) + lnb_j
  float acc = 0.f;
  for (int t = 0; t < 512; ++t) acc += ssc[t] * (float)hb[(size_t)t * 256 + tid];
  float att = lnw[tid] * (acc - PM) + lnb[tid];
  att_out[b * 256 + tid] = (f16)att;
}

// ---------------- launch ----------------

extern "C" void kernel_launch(void* const* d_in, const int* in_sizes, int n_in,
                              void* d_out, int out_size, void* d_ws, size_t ws_size,
                              hipStream_t stream) {
  (void)in_sizes; (void)n_in; (void)out_size; (void)ws_size;
  const float* x    = (const float*)d_in[0];
  const float* wih0 = (const float*)d_in[1];
  const float* whh0 = (const float*)d_in[2];
  const float* bih0 = (const float*)d_in[3];
  const float* bhh0 = (const float*)d_in[4];
  const float* wih1 = (const float*)d_in[5];
  const float* whh1 = (const float*)d_in[6];
  const float* bih1 = (const float*)d_in[7];
  const float* bhh1 = (const float*)d_in[8];
  const float* lnw  = (const float*)d_in[9];
  const float* lnb  = (const float*)d_in[10];
  const float* aw   = (const float*)d_in[11];
  const float* fcw  = (const float*)d_in[12];
  const float* fcb  = (const float*)d_in[13];

  char* ws = (char*)d_ws;
  f16* x_h      = (f16*)(ws + 0);            // 50331648 B; reused as h1/h2 after xg0
  f16* h1       = (f16*)(ws + 0);            // 16777216 B
  f16* h2       = (f16*)(ws + 16777216);     // 16777216 B
  f16* wih0_h   = (f16*)(ws + 50331648);     // 1572864
  f16* wih1_h   = (f16*)(ws + 51904512);     // 524288
  f16* fcw_h    = (f16*)(ws + 52428800);     // 15627264
  uint32_t* wp0 = (uint32_t*)(ws + 68056064);// 524288
  uint32_t* wp1 = (uint32_t*)(ws + 68580352);// 524288
  float* bsum0  = (float*)(ws + 69104640);   // 4096
  float* bsum1  = (float*)(ws + 69108736);   // 4096
  f16* att_h    = (f16*)(ws + 69112832);     // 32768
  f16* xg       = (f16*)(ws + 69145600);     // 67108864 (shared by both layers)

  f32_to_f16_kernel<<<4096, 256, 0, stream>>>(x, x_h, 25165824 / 4);
  f32_to_f16_kernel<<<768, 256, 0, stream>>>(wih0, wih0_h, 786432 / 4);
  f32_to_f16_kernel<<<256, 256, 0, stream>>>(wih1, wih1_h, 262144 / 4);
  f32_to_f16_kernel<<<2048, 256, 0, stream>>>(fcw, fcw_h, 7813632 / 4);
  addvec_kernel<<<4, 256, 0, stream>>>(bih0, bhh0, bsum0, 1024);
  addvec_kernel<<<4, 256, 0, stream>>>(bih1, bhh1, bsum1, 1024);
  wprep_kernel<<<512, 256, 0, stream>>>(whh0, wp0);
  wprep_kernel<<<512, 256, 0, stream>>>(whh1, wp1);

  // layer 0: xg0 = x @ w_ih0^T + (b_ih0 + b_hh0)
  gemm_bt_kernel<0><<<dim3(8, 256), 256, 0, stream>>>(x_h, wih0_h, bsum0, xg, 32768, 1024, 768);
  lstm_rec_kernel<<<64, 512, 0, stream>>>(xg, wp0, h1, 512);
  // layer 1
  gemm_bt_kernel<0><<<dim3(8, 256), 256, 0, stream>>>(h1, wih1_h, bsum1, xg, 32768, 1024, 256);
  lstm_rec_kernel<<<64, 512, 0, stream>>>(xg, wp1, h2, 512);
  // LN + attention pooling
  ln_attn_kernel<<<64, 256, 0, stream>>>(h2, lnw, lnb, aw, att_h);
  // FC: out = attended @ fc_w^T + fc_b  (fp32 out)
  gemm_bt_kernel<1><<<dim3(239, 1), 256, 0, stream>>>(att_h, fcw_h, fcb, d_out, 64, 30522, 256);
}

// Round 2
// 2158.114 us; speedup vs baseline: 1.1819x; 1.1819x over previous
//
#include <hip/hip_runtime.h>
#include <cstdint>

typedef _Float16 f16;
using f16x2 = __attribute__((ext_vector_type(2))) _Float16;
using f16x4 = __attribute__((ext_vector_type(4))) _Float16;
using f16x8 = __attribute__((ext_vector_type(8))) _Float16;
using f32x4 = __attribute__((ext_vector_type(4))) float;
using u32x4 = __attribute__((ext_vector_type(4))) uint32_t;

__device__ __forceinline__ float fdot2(uint32_t w, uint32_t h, float acc) {
#if __has_builtin(__builtin_amdgcn_fdot2)
  return __builtin_amdgcn_fdot2(__builtin_bit_cast(f16x2, w),
                                __builtin_bit_cast(f16x2, h), acc, false);
#else
  f16x2 a = __builtin_bit_cast(f16x2, w), b = __builtin_bit_cast(f16x2, h);
  return acc + (float)a[0] * (float)b[0] + (float)a[1] * (float)b[1];
#endif
}

__device__ __forceinline__ float sigmoidf_(float x) {
  float e = exp2f(-x * 1.44269504088896f);
  return 1.0f / (1.0f + e);
}
__device__ __forceinline__ float tanhf_(float x) {
  float e = exp2f(x * 2.88539008177793f);   // exp(2x)
  return 1.0f - 2.0f / (e + 1.0f);
}

// ---------------- conversion / prep kernels ----------------

__global__ void f32_to_f16_kernel(const float* __restrict__ in, f16* __restrict__ out, long n4) {
  long stride = (long)gridDim.x * blockDim.x;
  for (long i = blockIdx.x * (long)blockDim.x + threadIdx.x; i < n4; i += stride) {
    f32x4 v = *(const f32x4*)(in + i * 4);
    f16x4 h;
    h[0] = (f16)v[0]; h[1] = (f16)v[1]; h[2] = (f16)v[2]; h[3] = (f16)v[3];
    *(f16x4*)(out + i * 4) = h;
  }
}

__global__ void addvec_kernel(const float* __restrict__ a, const float* __restrict__ b,
                              float* __restrict__ o, int n) {
  int i = blockIdx.x * blockDim.x + threadIdx.x;
  if (i < n) o[i] = a[i] + b[i];
}

// wprep[p*1024 + r] = pack(whh[r][2p], whh[r][2p+1]) as f16x2, p<128, r<1024
__global__ void wprep_kernel(const float* __restrict__ whh, uint32_t* __restrict__ wp) {
  int i = blockIdx.x * blockDim.x + threadIdx.x;  // 131072 threads
  int p = i >> 10, r = i & 1023;
  float lo = whh[r * 256 + 2 * p];
  float hi = whh[r * 256 + 2 * p + 1];
  f16x2 h;
  h[0] = (f16)lo; h[1] = (f16)hi;
  wp[i] = __builtin_bit_cast(uint32_t, h);
}

// ---------------- GEMM: C[m,n] = sum_k A[m,k]*B[n,k] + bias[n] ----------------
// A [M,K] f16 row-major, B [N,K] f16 row-major. 128x128 tile, BK=32, 256 thr.

template <int OUTF32>
__global__ __launch_bounds__(256) void gemm_bt_kernel(
    const f16* __restrict__ A, const f16* __restrict__ B,
    const float* __restrict__ bias, void* __restrict__ Cout,
    int M, int N, int K) {
  __shared__ __align__(16) f16 Al[128 * 32];
  __shared__ __align__(16) f16 Bl[128 * 32];
  const int tid = threadIdx.x;
  const int lane = tid & 63, wave = tid >> 6;
  const int bn = blockIdx.x, bm = blockIdx.y;
  const int qm = (wave >> 1) * 64, qn = (wave & 1) * 64;

  f32x4 acc[4][4];
#pragma unroll
  for (int i = 0; i < 4; ++i)
#pragma unroll
    for (int j = 0; j < 4; ++j) acc[i][j] = (f32x4){0.f, 0.f, 0.f, 0.f};

  const int c0 = tid, c1 = 256 + tid;
  const int row0 = c0 >> 2, off0 = c0 & 3;
  const int row1 = c1 >> 2, off1 = c1 & 3;
  const int gmA0 = min(bm * 128 + row0, M - 1);
  const int gmA1 = min(bm * 128 + row1, M - 1);
  const int gnB0 = min(bn * 128 + row0, N - 1);
  const int gnB1 = min(bn * 128 + row1, N - 1);

  for (int k0 = 0; k0 < K; k0 += 32) {
    u32x4 ar0 = *(const u32x4*)(A + (size_t)gmA0 * K + k0 + off0 * 8);
    u32x4 ar1 = *(const u32x4*)(A + (size_t)gmA1 * K + k0 + off1 * 8);
    u32x4 br0 = *(const u32x4*)(B + (size_t)gnB0 * K + k0 + off0 * 8);
    u32x4 br1 = *(const u32x4*)(B + (size_t)gnB1 * K + k0 + off1 * 8);
    __syncthreads();  // previous iteration's LDS reads done
    *(u32x4*)&Al[c0 * 8] = ar0;
    *(u32x4*)&Al[c1 * 8] = ar1;
    *(u32x4*)&Bl[c0 * 8] = br0;
    *(u32x4*)&Bl[c1 * 8] = br1;
    __syncthreads();
    f16x8 af[4], bf[4];
#pragma unroll
    for (int mt = 0; mt < 4; ++mt)
      af[mt] = *(const f16x8*)&Al[(qm + mt * 16 + (lane & 15)) * 32 + (lane >> 4) * 8];
#pragma unroll
    for (int nt = 0; nt < 4; ++nt)
      bf[nt] = *(const f16x8*)&Bl[(qn + nt * 16 + (lane & 15)) * 32 + (lane >> 4) * 8];
#pragma unroll
    for (int mt = 0; mt < 4; ++mt)
#pragma unroll
      for (int nt = 0; nt < 4; ++nt)
        acc[mt][nt] = __builtin_amdgcn_mfma_f32_16x16x32_f16(af[mt], bf[nt], acc[mt][nt], 0, 0, 0);
  }

#pragma unroll
  for (int mt = 0; mt < 4; ++mt)
#pragma unroll
    for (int nt = 0; nt < 4; ++nt)
#pragma unroll
      for (int j = 0; j < 4; ++j) {
        int gm = bm * 128 + qm + mt * 16 + (lane >> 4) * 4 + j;
        int gn = bn * 128 + qn + nt * 16 + (lane & 15);
        if (gm < M && gn < N) {
          float v = acc[mt][nt][j] + bias[gn];
          if (OUTF32)
            ((float*)Cout)[(size_t)gm * N + gn] = v;
          else
            ((f16*)Cout)[(size_t)gm * N + gn] = (f16)v;
        }
      }
}

// ---------------- persistent LSTM recurrence ----------------
// 64 blocks (1 batch each) x 512 threads, __launch_bounds__(512,2) -> 256 VGPR cap.
// Wave w, lanes 0-31 own (i_j, g_j), lanes 32-63 own (f_j, o_j), j = w*32+(l&31).
// Gate exchange via __shfl_xor(32); both lanes redundantly compute c_j, h_j.
// h double-buffered in LDS -> ONE raw s_barrier per step, lgkmcnt-only wait
// (global h-store and x-prefetch are never drained inside the loop).
// Weights: pairs 0..RP-1 in VGPR, RP..127 in LDS (stride LSTRIDE dwords, 16B aligned).

#define RP 104
#define LP 24
#define LSTRIDE 28

__global__ __launch_bounds__(512, 2) void lstm_rec_kernel(
    const f16* __restrict__ xg,          // [B*T, 1024], biases already included
    const uint32_t* __restrict__ wprep,  // [128][1024] packed f16x2
    f16* __restrict__ h_out,             // [B*T, 256]
    int T) {
  __shared__ uint32_t lds_w[1024 * LSTRIDE];        // 112 KB
  __shared__ __align__(16) uint32_t h_buf[2][128];  // 1 KB, double-buffered h
  const int b = blockIdx.x;
  const int tid = threadIdx.x;
  const int wave = tid >> 6, lane = tid & 63;
  const int l32 = lane & 31, half = lane >> 5;
  const int j = wave * 32 + l32;        // hidden unit owned (redundantly by the pair)
  const int row0 = half * 256 + j;      // half0: i_j ; half1: f_j
  const int row1 = row0 + 512;          // half0: g_j ; half1: o_j

  uint32_t w0[RP], w1[RP];
#pragma unroll
  for (int p = 0; p < RP; ++p) {
    w0[p] = wprep[p * 1024 + row0];
    w1[p] = wprep[p * 1024 + row1];
  }
#pragma unroll
  for (int p = 0; p < LP; ++p) {
    lds_w[row0 * LSTRIDE + p] = wprep[(RP + p) * 1024 + row0];
    lds_w[row1 * LSTRIDE + p] = wprep[(RP + p) * 1024 + row1];
  }
  if (tid < 256) ((uint32_t*)h_buf)[tid] = 0;  // zero both h buffers
  float c_state = 0.0f;
  __syncthreads();

  const f16* xgb = xg + (size_t)b * T * 1024;
  f16* hob = h_out + (size_t)b * T * 256;
  f16 xr0 = xgb[row0], xr1 = xgb[row1];

  for (int t = 0; t < T; ++t) {
    // prefetch next step's x-gate contributions (consumed next iter; no drain)
    int tn = (t + 1 < T) ? t + 1 : T - 1;
    f16 nx0 = xgb[(size_t)tn * 1024 + row0];
    f16 nx1 = xgb[(size_t)tn * 1024 + row1];

    const u32x4* hq = (const u32x4*)h_buf[t & 1];
    float a0 = (float)xr0, a1 = (float)xr1;  // even-q chains
    float e0 = 0.f, e1 = 0.f;                // odd-q chains
    // LDS-resident weight chunks first (reads issue early, overlap VGPR chunks)
#pragma unroll
    for (int cc = 0; cc < LP / 4; ++cc) {
      u32x4 hv = hq[RP / 4 + cc];
      u32x4 wv0 = *(const u32x4*)&lds_w[row0 * LSTRIDE + cc * 4];
      u32x4 wv1 = *(const u32x4*)&lds_w[row1 * LSTRIDE + cc * 4];
#pragma unroll
      for (int q = 0; q < 4; ++q) {
        if (q & 1) { e0 = fdot2(wv0[q], hv[q], e0); e1 = fdot2(wv1[q], hv[q], e1); }
        else       { a0 = fdot2(wv0[q], hv[q], a0); a1 = fdot2(wv1[q], hv[q], a1); }
      }
    }
#pragma unroll
    for (int ch = 0; ch < RP / 4; ++ch) {
      u32x4 hv = hq[ch];
#pragma unroll
      for (int q = 0; q < 4; ++q) {
        const int p = ch * 4 + q;
        if (q & 1) { e0 = fdot2(w0[p], hv[q], e0); e1 = fdot2(w1[p], hv[q], e1); }
        else       { a0 = fdot2(w0[p], hv[q], a0); a1 = fdot2(w1[p], hv[q], a1); }
      }
    }
    float g0 = a0 + e0, g1 = a1 + e1;
    float p0 = __shfl_xor(g0, 32, 64);
    float p1 = __shfl_xor(g1, 32, 64);
    // branchless gate selection (avoid half-wave divergence)
    float x_i = half ? p0 : g0;
    float x_f = half ? g0 : p0;
    float x_g = half ? p1 : g1;
    float x_o = half ? g1 : p1;
    float iv = sigmoidf_(x_i), fv = sigmoidf_(x_f);
    float gv = tanhf_(x_g),   ov = sigmoidf_(x_o);
    c_state = fv * c_state + iv * gv;
    float hval = ov * tanhf_(c_state);
    f16 hh = (f16)hval;
    if (half == 0) {
      ((f16*)h_buf[(t + 1) & 1])[j] = hh;      // publish h for next step
    } else {
      hob[(size_t)t * 256 + j] = hh;           // global h output (never drained in-loop)
    }
    xr0 = nx0; xr1 = nx1;
    asm volatile("s_waitcnt lgkmcnt(0)" ::: "memory");  // h writes visible
    __builtin_amdgcn_s_barrier();                        // single barrier per step
    __builtin_amdgcn_sched_barrier(0);                   // no hoisting of next-step LDS reads
  }
}

// ---------------- fused LayerNorm + attention pooling ----------------
// one block per batch, 256 threads.

__global__ __launch_bounds__(256) void ln_attn_kernel(
    const f16* __restrict__ h2, const float* __restrict__ lnw,
    const float* __restrict__ lnb, const float* __restrict__ aw,
    f16* __restrict__ att_out) {
  const int b = blockIdx.x, tid = threadIdx.x;
  const int lane = tid & 63, wave = tid >> 6;
  __shared__ float smu[512], sis[512], ssc[512];
  __shared__ float vbuf[256];
  __shared__ float red[16];

  float vj = aw[tid] * lnw[tid];
  float uj = aw[tid] * lnb[tid];
  vbuf[tid] = vj;
  float rv = vj, ru = uj;
#pragma unroll
  for (int m = 1; m < 64; m <<= 1) { rv += __shfl_xor(rv, m, 64); ru += __shfl_xor(ru, m, 64); }
  if (lane == 0) { red[wave] = rv; red[4 + wave] = ru; }
  __syncthreads();
  const float Vsum = red[0] + red[1] + red[2] + red[3];
  const float Csum = red[4] + red[5] + red[6] + red[7];
  const f32x4 v4 = *(const f32x4*)&vbuf[lane * 4];
  const f16* hb = h2 + (size_t)b * 512 * 256;

  for (int tt = wave; tt < 512; tt += 4) {
    f16x4 hv = *(const f16x4*)(hb + (size_t)tt * 256 + lane * 4);
    float h0 = (float)hv[0], h1 = (float)hv[1], h2v = (float)hv[2], h3 = (float)hv[3];
    float s1 = h0 + h1 + h2v + h3;
    float s2 = h0 * h0 + h1 * h1 + h2v * h2v + h3 * h3;
    float sv = h0 * v4[0] + h1 * v4[1] + h2v * v4[2] + h3 * v4[3];
#pragma unroll
    for (int m = 1; m < 64; m <<= 1) {
      s1 += __shfl_xor(s1, m, 64);
      s2 += __shfl_xor(s2, m, 64);
      sv += __shfl_xor(sv, m, 64);
    }
    if (lane == 0) {
      float mu = s1 * (1.0f / 256.0f);
      float var = s2 * (1.0f / 256.0f) - mu * mu;
      float is = rsqrtf(var + 1e-5f);
      smu[tt] = mu; sis[tt] = is;
      ssc[tt] = (sv - mu * Vsum) * is + Csum;
    }
  }
  __syncthreads();
  // softmax over 512 scores
  float a0 = ssc[tid], a1 = ssc[tid + 256];
  float mx = fmaxf(a0, a1);
#pragma unroll
  for (int m = 1; m < 64; m <<= 1) mx = fmaxf(mx, __shfl_xor(mx, m, 64));
  if (lane == 0) red[wave] = mx;
  __syncthreads();
  mx = fmaxf(fmaxf(red[0], red[1]), fmaxf(red[2], red[3]));
  __syncthreads();  // protect red reuse
  float p0 = exp2f((a0 - mx) * 1.44269504f);
  float p1 = exp2f((a1 - mx) * 1.44269504f);
  float ps = p0 + p1;
  float pm = p0 * smu[tid] * sis[tid] + p1 * smu[tid + 256] * sis[tid + 256];
#pragma unroll
  for (int m = 1; m < 64; m <<= 1) { ps += __shfl_xor(ps, m, 64); pm += __shfl_xor(pm, m, 64); }
  if (lane == 0) { red[wave] = ps; red[8 + wave] = pm; }
  __syncthreads();
  const float S = red[0] + red[1] + red[2] + red[3];
  const float PM = (red[8] + red[9] + red[10] + red[11]) / S;
  ssc[tid] = p0 / S * sis[tid];          // alpha_t
  ssc[tid + 256] = p1 / S * sis[tid + 256];
  __syncthreads();
  // pass 2: attended_j = lnw_j*(sum_t alpha_t h_tj - PM) + lnb_j
  float acc = 0.f;
  for (int t = 0; t < 512; ++t) acc += ssc[t] * (float)hb[(size_t)t * 256 + tid];
  float att = lnw[tid] * (acc - PM) + lnb[tid];
  att_out[b * 256 + tid] = (f16)att;
}

// ---------------- launch ----------------

extern "C" void kernel_launch(void* const* d_in, const int* in_sizes, int n_in,
                              void* d_out, int out_size, void* d_ws, size_t ws_size,
                              hipStream_t stream) {
  (void)in_sizes; (void)n_in; (void)out_size; (void)ws_size;
  const float* x    = (const float*)d_in[0];
  const float* wih0 = (const float*)d_in[1];
  const float* whh0 = (const float*)d_in[2];
  const float* bih0 = (const float*)d_in[3];
  const float* bhh0 = (const float*)d_in[4];
  const float* wih1 = (const float*)d_in[5];
  const float* whh1 = (const float*)d_in[6];
  const float* bih1 = (const float*)d_in[7];
  const float* bhh1 = (const float*)d_in[8];
  const float* lnw  = (const float*)d_in[9];
  const float* lnb  = (const float*)d_in[10];
  const float* aw   = (const float*)d_in[11];
  const float* fcw  = (const float*)d_in[12];
  const float* fcb  = (const float*)d_in[13];

  char* ws = (char*)d_ws;
  f16* x_h      = (f16*)(ws + 0);            // 50331648 B; reused as h1/h2 after xg0
  f16* h1       = (f16*)(ws + 0);            // 16777216 B
  f16* h2       = (f16*)(ws + 16777216);     // 16777216 B
  f16* wih0_h   = (f16*)(ws + 50331648);     // 1572864
  f16* wih1_h   = (f16*)(ws + 51904512);     // 524288
  f16* fcw_h    = (f16*)(ws + 52428800);     // 15627264
  uint32_t* wp0 = (uint32_t*)(ws + 68056064);// 524288
  uint32_t* wp1 = (uint32_t*)(ws + 68580352);// 524288
  float* bsum0  = (float*)(ws + 69104640);   // 4096
  float* bsum1  = (float*)(ws + 69108736);   // 4096
  f16* att_h    = (f16*)(ws + 69112832);     // 32768
  f16* xg       = (f16*)(ws + 69145600);     // 67108864 (shared by both layers)

  f32_to_f16_kernel<<<4096, 256, 0, stream>>>(x, x_h, 25165824 / 4);
  f32_to_f16_kernel<<<768, 256, 0, stream>>>(wih0, wih0_h, 786432 / 4);
  f32_to_f16_kernel<<<256, 256, 0, stream>>>(wih1, wih1_h, 262144 / 4);
  f32_to_f16_kernel<<<2048, 256, 0, stream>>>(fcw, fcw_h, 7813632 / 4);
  addvec_kernel<<<4, 256, 0, stream>>>(bih0, bhh0, bsum0, 1024);
  addvec_kernel<<<4, 256, 0, stream>>>(bih1, bhh1, bsum1, 1024);
  wprep_kernel<<<512, 256, 0, stream>>>(whh0, wp0);
  wprep_kernel<<<512, 256, 0, stream>>>(whh1, wp1);

  // layer 0: xg0 = x @ w_ih0^T + (b_ih0 + b_hh0)
  gemm_bt_kernel<0><<<dim3(8, 256), 256, 0, stream>>>(x_h, wih0_h, bsum0, xg, 32768, 1024, 768);
  lstm_rec_kernel<<<64, 512, 0, stream>>>(xg, wp0, h1, 512);
  // layer 1
  gemm_bt_kernel<0><<<dim3(8, 256), 256, 0, stream>>>(h1, wih1_h, bsum1, xg, 32768, 1024, 256);
  lstm_rec_kernel<<<64, 512, 0, stream>>>(xg, wp1, h2, 512);
  // LN + attention pooling
  ln_attn_kernel<<<64, 256, 0, stream>>>(h2, lnw, lnb, aw, att_h);
  // FC: out = attended @ fc_w^T + fc_b  (fp32 out)
  gemm_bt_kernel<1><<<dim3(239, 1), 256, 0, stream>>>(att_h, fcw_h, fcb, d_out, 64, 30522, 256);
}